// Round 14
// baseline (65.409 us; speedup 1.0000x reference)
//
#include <hip/hip_runtime.h>
#include <math.h>

#define FRAME_LEN 512
#define HOP       256
#define NFREQ     257
#define NBATCH    64
#define NSAMP     160000
#define TFRAMES   624
#define EPS       1.1920928955078125e-07f

#define MT 128                 // frames per tile; 312 M-tiles
#define FT 32                  // freq bins per tile; 5 f-tiles (f 0..128 pad 160)
#define KH 256                 // K per parity (table row length)

typedef __attribute__((ext_vector_type(8))) short short8;   // 8 bf16
typedef __attribute__((ext_vector_type(4))) float f32x4;    // MFMA acc

static __device__ __forceinline__ unsigned int f2bf(float f) {
    unsigned int u = __float_as_uint(f);
    return (u + 0x7fffu + ((u >> 16) & 1u)) >> 16;          // RNE to bf16
}
static __device__ __forceinline__ void gload_lds16(const void* g, void* l) {
    __builtin_amdgcn_global_load_lds(
        (const __attribute__((address_space(1))) void*)g,
        (__attribute__((address_space(3))) void*)l, 16, 0, 0);
}

// ---------------- tables only: [160][256] bf16 parity DFT kernels -----------
__global__ __launch_bounds__(256) void prep_tables(unsigned short* __restrict__ Wec,
                                                   unsigned short* __restrict__ Wes,
                                                   unsigned short* __restrict__ Woc,
                                                   unsigned short* __restrict__ Wos) {
    int f = blockIdx.x;                         // 0..159 (f<=128 live)
    int n2 = threadIdx.x;                       // n' 0..255
    unsigned short ec = 0, es = 0, oc = 0, os = 0;
    if (f <= 128) {
        int ne = 2 * n2, no = 2 * n2 + 1;
        float we = 0.5f * (1.0f - cosf(2.0f * (float)M_PI * (float)ne / (float)FRAME_LEN));
        float wo = 0.5f * (1.0f - cosf(2.0f * (float)M_PI * (float)no / (float)FRAME_LEN));
        float ange = (float)((f * ne) & (FRAME_LEN - 1)) * (2.0f * (float)M_PI / (float)FRAME_LEN);
        float ango = (float)((f * no) & (FRAME_LEN - 1)) * (2.0f * (float)M_PI / (float)FRAME_LEN);
        float se_, ce_, so_, co_;
        sincosf(ange, &se_, &ce_);
        sincosf(ango, &so_, &co_);
        ec = (unsigned short)f2bf(ce_ * we);
        es = (unsigned short)f2bf(se_ * we);    // i = +sin*w convention
        oc = (unsigned short)f2bf(co_ * wo);
        os = (unsigned short)f2bf(so_ * wo);
    }
    Wec[f * KH + n2] = ec; Wes[f * KH + n2] = es;
    Woc[f * KH + n2] = oc; Wos[f * KH + n2] = os;
}

// ------ stft fused: f32 x read + bf16 parity-split staging + mirror MFMA ----
// A layout As[row 128][parity 2][64] bf16 (single buffer, wave-local rows).
// Staging: 16 stripe-steps/window; lane -> (row rb+2j, 16B at co*4 f32) —
// coalesced 512B per 32-lane group. Convert in-reg; e/o b32 stores hit all
// 32 banks (cc-XOR swizzle + wi spread). Reads identical to r10 (2-way free).
__global__ __launch_bounds__(256) void stft_fused(
    const float* __restrict__ x,
    const unsigned short* __restrict__ Wec, const unsigned short* __restrict__ Wes,
    const unsigned short* __restrict__ Woc, const unsigned short* __restrict__ Wos,
    float* __restrict__ mag)
{
    __shared__ unsigned short As[MT][2][64];    // 32 KB single-buffered
    __shared__ unsigned short Bs[2][2][FT][64]; // 16 KB dbuf (cos,sin)

    const int tid = threadIdx.x;
    // XCD swizzle: nwg=1560=8*195; 5 consecutive logicals share an A-tile.
    const int logical = ((int)blockIdx.x & 7) * 195 + ((int)blockIdx.x >> 3);
    const int tileM = logical / 5;              // 0..311
    const int tileF = logical % 5;              // 0..4
    const int wid = tid >> 6;
    const int lane = tid & 63;
    const int lrow = lane & 15;
    const int lhi = lane >> 4;

    unsigned short* AsB = &As[0][0][0];
    unsigned short* BsB = &Bs[0][0][0][0];

    // A staging lane geometry (wave-local rows wid*32 .. wid*32+31)
    const int rb = wid * 32 + (lane >> 5);      // row base (+2j per step)
    const int co = lane & 31;                   // 16B slot within 512B stripe
    const int cc = co >> 2;                     // e/o chunk 0..7
    const int wi = co & 3;                      // u32 slot within chunk

    // B staging sources (source chunk-XOR; linear gload dest) — r10 scheme
    const unsigned short* pB[2][2];
    #pragma unroll
    for (int j = 0; j < 2; j++) {
        int i = wid * 2 + j;                    // 0..7: 0-3 cos, 4-7 sin
        int row = (i & 3) * 8 + (lane >> 3);
        int fg = tileF * FT + row;              // < 160 (padded tables)
        int chunk = (lane & 7) ^ (row & 7);
        size_t off = (size_t)fg * KH + chunk * 8;
        pB[0][j] = ((i & 4) ? Wes : Wec) + off;
        pB[1][j] = ((i & 4) ? Wos : Woc) + off;
    }

    f32x4 aC[2][2][2] = {};                     // [parity][mf][nf]
    f32x4 aS[2][2][2] = {};
    float4 av[16];

    // ---- A-stage helpers (unrolled via macros on compile-time w) ----
#define LOADW(w)                                                              \
    _Pragma("unroll")                                                         \
    for (int j = 0; j < 16; j++) {                                            \
        int r = rb + 2 * j;                                                   \
        int m = tileM * MT + r;                                               \
        int bb = m / TFRAMES; int tt = m - bb * TFRAMES;                      \
        av[j] = *(const float4*)(x + (size_t)bb * NSAMP + tt * HOP + (w) * 128 + co * 4); \
    }
#define CVTW()                                                                \
    _Pragma("unroll")                                                         \
    for (int j = 0; j < 16; j++) {                                            \
        int r = rb + 2 * j;                                                   \
        unsigned int e32 = f2bf(av[j].x) | (f2bf(av[j].z) << 16);             \
        unsigned int o32 = f2bf(av[j].y) | (f2bf(av[j].w) << 16);             \
        unsigned int* ep = (unsigned int*)(AsB + r * 128 + ((cc ^ (r & 7)) * 8 + wi * 2)); \
        ep[0]  = e32;   /* As[r][0][..] */                                    \
        ep[32] = o32;   /* As[r][1][..] (+64 shorts) */                       \
    }
#define COMPUTE(p, sl)                                                        \
    _Pragma("unroll")                                                         \
    for (int ks = 0; ks < 2; ks++) {                                          \
        short8 a[2], bc[2], bsn[2];                                           \
        const int ci = (ks * 4 + lhi) ^ (lrow & 7);                           \
        _Pragma("unroll")                                                     \
        for (int mf = 0; mf < 2; mf++)                                        \
            a[mf] = *(const short8*)(AsB + (wid * 32 + mf * 16 + lrow) * 128 + (p) * 64 + ci * 8); \
        _Pragma("unroll")                                                     \
        for (int nf = 0; nf < 2; nf++) {                                      \
            bc[nf]  = *(const short8*)(BsB + (sl) * 4096 + (nf * 16 + lrow) * 64 + ci * 8); \
            bsn[nf] = *(const short8*)(BsB + (sl) * 4096 + 2048 + (nf * 16 + lrow) * 64 + ci * 8); \
        }                                                                     \
        _Pragma("unroll")                                                     \
        for (int mf = 0; mf < 2; mf++) {                                      \
            _Pragma("unroll")                                                 \
            for (int nf = 0; nf < 2; nf++) {                                  \
                aC[p][mf][nf] = __builtin_amdgcn_mfma_f32_16x16x32_bf16(      \
                    a[mf], bc[nf], aC[p][mf][nf], 0, 0, 0);                   \
                aS[p][mf][nf] = __builtin_amdgcn_mfma_f32_16x16x32_bf16(      \
                    a[mf], bsn[nf], aS[p][mf][nf], 0, 0, 0);                  \
            }                                                                 \
        }                                                                     \
    }
#define ISSUE_B(p, sl, w)                                                     \
    _Pragma("unroll")                                                         \
    for (int j = 0; j < 2; j++)                                               \
        gload_lds16(pB[p][j] + (w) * 64, BsB + (sl) * 4096 + (wid * 2 + j) * 512);

    // ---- prologue: B(e,0) + A-window 0 (both parities), then barrier
    ISSUE_B(0, 0, 0);
    LOADW(0);
    CVTW();
    __syncthreads();

    // ---- 8 iterations: even = (e,w) from Bs[0]; odd = (o,w) from Bs[1].
    // Odd iters also: load window w+1 (before compute), stage B(e,w+1),
    // convert+write w+1 after compute (in-order DS => no WAR on As).
    #pragma unroll
    for (int it = 0; it < 8; it++) {
        const int w = it >> 1;
        if ((it & 1) == 0) {
            ISSUE_B(1, 1, w);                   // (o,w) tables -> Bs[1]
            COMPUTE(0, 0);                      // (e,w)
            __syncthreads();
        } else {
            if (w < 3) {
                ISSUE_B(0, 0, w + 1);           // (e,w+1) tables -> Bs[0]
                if (w == 0)      { LOADW(1); }
                else if (w == 1) { LOADW(2); }
                else             { LOADW(3); }
            }
            COMPUTE(1, 1);                      // (o,w) — reads issued first
            if (w < 3) { CVTW(); }              // then overwrite As with w+1
            if (it < 7) __syncthreads();
        }
    }

    // ---- epilogue: f (<=128) direct, 256-f mirror; float4 over 4 t
    #pragma unroll
    for (int mf = 0; mf < 2; mf++) {
        int m0 = tileM * MT + wid * 32 + mf * 16 + lhi * 4;
        int b = m0 / TFRAMES;
        int t = m0 - b * TFRAMES;               // %4==0, run stays in batch
        #pragma unroll
        for (int nf = 0; nf < 2; nf++) {
            int f = tileF * FT + nf * 16 + lrow;
            float4 od, om;
            #pragma unroll
            for (int q = 0; q < 4; q++) {
                const float Ce = aC[0][mf][nf][q], Co = aC[1][mf][nf][q];
                const float Se = aS[0][mf][nf][q], So = aS[1][mf][nf][q];
                const float rd = Ce + Co, id = Se + So;
                const float rm = Ce - Co, im = So - Se;
                (&od.x)[q] = sqrtf(rd * rd + id * id);
                (&om.x)[q] = sqrtf(rm * rm + im * im);
            }
            if (f <= 128)
                *(float4*)(mag + ((size_t)b * NFREQ + f) * TFRAMES + t) = od;
            if (f <= 127)
                *(float4*)(mag + ((size_t)b * NFREQ + (256 - f)) * TFRAMES + t) = om;
        }
    }
#undef LOADW
#undef CVTW
#undef COMPUTE
#undef ISSUE_B
}

// ------------------------------------------- normalize: warp-per-row, f4 ----
__global__ __launch_bounds__(256) void normalize(const float* __restrict__ mag,
                                                 float* __restrict__ feat)
{
    const int row = blockIdx.x * 4 + (threadIdx.x >> 6);    // b*NFREQ+f
    const int lane = threadIdx.x & 63;
    const float* mp = mag + (size_t)row * TFRAMES;

    float4 v[3];
    float sum = 0.f;
    #pragma unroll
    for (int i = 0; i < 3; i++) {
        int c4 = lane + i * 64;                 // 156 float4 per row
        if (c4 < TFRAMES / 4) {
            float4 t = *(const float4*)(mp + c4 * 4);
            t.x = fmaxf(t.x, EPS); t.y = fmaxf(t.y, EPS);
            t.z = fmaxf(t.z, EPS); t.w = fmaxf(t.w, EPS);
            v[i] = t;
            sum += (t.x + t.y) + (t.z + t.w);
        } else {
            v[i] = make_float4(0.f, 0.f, 0.f, 0.f);
        }
    }
    #pragma unroll
    for (int off = 1; off < 64; off <<= 1) sum += __shfl_xor(sum, off, 64);
    const float mean = sum * (1.0f / (float)TFRAMES);

    float ssd = 0.f;
    #pragma unroll
    for (int i = 0; i < 3; i++) {
        int c4 = lane + i * 64;
        if (c4 < TFRAMES / 4) {
            float dx = v[i].x - mean, dy = v[i].y - mean;
            float dz = v[i].z - mean, dw = v[i].w - mean;
            ssd += (dx * dx + dy * dy) + (dz * dz + dw * dw);
        }
    }
    #pragma unroll
    for (int off = 1; off < 64; off <<= 1) ssd += __shfl_xor(ssd, off, 64);
    const float stdv = sqrtf(ssd * (1.0f / (float)(TFRAMES - 1)));
    const float inv = 1.0f / (stdv + EPS);

    float* fp = feat + (size_t)row * TFRAMES;
    #pragma unroll
    for (int i = 0; i < 3; i++) {
        int c4 = lane + i * 64;
        if (c4 < TFRAMES / 4) {
            float4 o;
            o.x = (v[i].x - mean) * inv; o.y = (v[i].y - mean) * inv;
            o.z = (v[i].z - mean) * inv; o.w = (v[i].w - mean) * inv;
            *(float4*)(fp + c4 * 4) = o;
        }
    }
}

// ---------------------------------------------------------------- launch ----
extern "C" void kernel_launch(void* const* d_in, const int* in_sizes, int n_in,
                              void* d_out, int out_size, void* d_ws, size_t ws_size,
                              hipStream_t stream) {
    const float* x = (const float*)d_in[0];
    unsigned short* Wec = (unsigned short*)d_ws;            // [160][256] bf16
    unsigned short* Wes = Wec + 160 * KH;
    unsigned short* Woc = Wes + 160 * KH;
    unsigned short* Wos = Woc + 160 * KH;
    float* mag  = (float*)d_out;                            // [64][257][624]
    float* feat = mag + (size_t)NBATCH * NFREQ * TFRAMES;

    prep_tables<<<160, 256, 0, stream>>>(Wec, Wes, Woc, Wos);

    // 312 M-tiles x 5 F-tiles, linearized + XCD-swizzled in-kernel
    stft_fused<<<312 * 5, 256, 0, stream>>>(x, Wec, Wes, Woc, Wos, mag);

    normalize<<<NBATCH * NFREQ / 4, 256, 0, stream>>>(mag, feat);
}

// Round 15
// 58.615 us; speedup vs baseline: 1.1159x; 1.1159x over previous
//
#include <hip/hip_runtime.h>
#include <math.h>

#define FRAME_LEN 512
#define HOP       256
#define NFREQ     257
#define NBATCH    64
#define NSAMP     160000
#define TFRAMES   624
#define EPS       1.1920928955078125e-07f

#define MT 128                 // frames per tile; 312 M-tiles
#define FT 32                  // freq bins per tile; 5 f-tiles (f 0..128 pad 160)
#define KH 256                 // K per parity (table row length)
#define XBLKS 5000             // x-transpose blocks (8 samples/thread)
#define BSZ (2 * FT * 64)      // shorts per B buffer (4096)

// xT layout: [msub 2496][parity 2][chunk 8][row 16][k 32] bf16 (40.9 MB).
// A wave's MFMA A-fragment = one contiguous 1024B slice of a subtile.

typedef __attribute__((ext_vector_type(8))) short short8;   // 8 bf16
typedef __attribute__((ext_vector_type(4))) float f32x4;    // MFMA acc

static __device__ __forceinline__ unsigned int f2bf(float f) {
    unsigned int u = __float_as_uint(f);
    return (u + 0x7fffu + ((u >> 16) & 1u)) >> 16;          // RNE to bf16
}
static __device__ __forceinline__ void gload_lds16(const void* g, void* l) {
    __builtin_amdgcn_global_load_lds(
        (const __attribute__((address_space(1))) void*)g,
        (__attribute__((address_space(3))) void*)l, 16, 0, 0);
}

// ---- prep: x -> xT (fragment-order, parity-split, 2x frame overlap)
//      + 4 parity DFT tables [160][256] bf16 -------------------------------
__global__ __launch_bounds__(256) void prep(const float* __restrict__ x,
                                            unsigned short* __restrict__ xT,
                                            unsigned short* __restrict__ Wec,
                                            unsigned short* __restrict__ Wes,
                                            unsigned short* __restrict__ Woc,
                                            unsigned short* __restrict__ Wos) {
    if (blockIdx.x < XBLKS) {
        const int i = blockIdx.x * 256 + threadIdx.x;
        const int g = i * 8;                    // global sample id
        const int b = g / NSAMP;
        const int s = g - b * NSAMP;            // sample within batch
        const float4* src = (const float4*)(x + (size_t)b * NSAMP + s);
        const float4 v0 = src[0], v1 = src[1];
        uint2 e, o;
        e.x = f2bf(v0.x) | (f2bf(v0.z) << 16);
        e.y = f2bf(v1.x) | (f2bf(v1.z) << 16);
        o.x = f2bf(v0.y) | (f2bf(v0.w) << 16);
        o.y = f2bf(v1.y) | (f2bf(v1.w) << 16);
        const int t0 = s >> 8;                  // frame whose FIRST half holds s
        const int k0 = s & 255;                 // k within that first half
        const int ch = k0 >> 6;                 // chunk 0..3 (k' = k0/2, /32)
        const int cpos = (k0 >> 1) & 31;        // k' slot, multiple of 4
        if (t0 < TFRAMES) {                     // first half of frame t0
            size_t base = ((((size_t)(b * 39 + (t0 >> 4)) * 2) * 8 + ch) * 512)
                          + (t0 & 15) * 32 + cpos;
            *(uint2*)(xT + base) = e;           // parity 0
            *(uint2*)(xT + base + 4096) = o;    // parity 1 (+8*512 shorts)
        }
        const int t1 = t0 - 1;                  // frame whose SECOND half holds s
        if (t1 >= 0) {
            size_t base = ((((size_t)(b * 39 + (t1 >> 4)) * 2) * 8 + (ch + 4)) * 512)
                          + (t1 & 15) * 32 + cpos;
            *(uint2*)(xT + base) = e;
            *(uint2*)(xT + base + 4096) = o;
        }
    } else {                                    // tables [160][256], f<=128 live
        int f = blockIdx.x - XBLKS;             // 0..159
        int n2 = threadIdx.x;                   // n' 0..255
        unsigned short ec = 0, es = 0, oc = 0, os = 0;
        if (f <= 128) {
            int ne = 2 * n2, no = 2 * n2 + 1;
            float we = 0.5f * (1.0f - cosf(2.0f * (float)M_PI * (float)ne / (float)FRAME_LEN));
            float wo = 0.5f * (1.0f - cosf(2.0f * (float)M_PI * (float)no / (float)FRAME_LEN));
            float ange = (float)((f * ne) & (FRAME_LEN - 1)) * (2.0f * (float)M_PI / (float)FRAME_LEN);
            float ango = (float)((f * no) & (FRAME_LEN - 1)) * (2.0f * (float)M_PI / (float)FRAME_LEN);
            float se_, ce_, so_, co_;
            sincosf(ange, &se_, &ce_);
            sincosf(ango, &so_, &co_);
            ec = (unsigned short)f2bf(ce_ * we);
            es = (unsigned short)f2bf(se_ * we);    // i = +sin*w convention
            oc = (unsigned short)f2bf(co_ * wo);
            os = (unsigned short)f2bf(so_ * wo);
        }
        Wec[f * KH + n2] = ec; Wes[f * KH + n2] = es;
        Woc[f * KH + n2] = oc; Wos[f * KH + n2] = os;
    }
}

// ---- stft: mirror MFMA, A direct-from-global (fragment order), B-only LDS --
__global__ __launch_bounds__(256, 3) void stft_mfma(
    const unsigned short* __restrict__ xT,
    const unsigned short* __restrict__ Wec, const unsigned short* __restrict__ Wes,
    const unsigned short* __restrict__ Woc, const unsigned short* __restrict__ Wos,
    float* __restrict__ mag)
{
    __shared__ unsigned short Bs[2][2][FT][64]; // 16 KB dbuf only

    const int tid = threadIdx.x;
    // XCD swizzle: nwg=1560=8*195; 5 consecutive logicals share an A-tile.
    const int logical = ((int)blockIdx.x & 7) * 195 + ((int)blockIdx.x >> 3);
    const int tileM = logical / 5;              // 0..311
    const int tileF = logical % 5;              // 0..4
    const int wid = tid >> 6;
    const int lane = tid & 63;
    const int lrow = lane & 15;
    const int lhi = lane >> 4;

    unsigned short* BsB = &Bs[0][0][0][0];

    // A: per-mf fragment base (parity/chunk fold into compile-time offsets)
    const unsigned short* pA[2];
    #pragma unroll
    for (int mf = 0; mf < 2; mf++) {
        int msub = tileM * 8 + wid * 2 + mf;    // global 16-row subtile id
        pA[mf] = xT + (size_t)msub * 8192 + lrow * 32 + lhi * 8;
    }
    // B staging sources (source chunk-XOR; linear gload dest) — r10 scheme
    const unsigned short* pB[2][2];
    #pragma unroll
    for (int j = 0; j < 2; j++) {
        int i = wid * 2 + j;                    // 0..7: 0-3 cos, 4-7 sin
        int row = (i & 3) * 8 + (lane >> 3);
        int fg = tileF * FT + row;              // < 160 (padded tables)
        int chunk = (lane & 7) ^ (row & 7);
        size_t off = (size_t)fg * KH + chunk * 8;
        pB[0][j] = ((i & 4) ? Wes : Wec) + off;
        pB[1][j] = ((i & 4) ? Wos : Woc) + off;
    }

    f32x4 aC[2][2][2] = {};                     // [parity][mf][nf]
    f32x4 aS[2][2][2] = {};

    // ---- prologue: stage B(parity 0, k-chunk 0) into buf 0
    #pragma unroll
    for (int j = 0; j < 2; j++)
        gload_lds16(pB[0][j], BsB + (wid * 2 + j) * 512);
    __syncthreads();

    int buf = 0;
    #pragma unroll
    for (int it = 0; it < 8; it++) {
        const int p = it >> 2;                  // parity (compile-time)
        const int kc = it & 3;                  // 64-k chunk within parity
        // ---- stage next B chunk into other buffer
        if (it < 7) {
            const int pn = (it + 1) >> 2;
            const int kn = ((it + 1) & 3) * 64;
            #pragma unroll
            for (int j = 0; j < 2; j++)
                gload_lds16(pB[pn][j] + kn, BsB + (buf ^ 1) * BSZ + (wid * 2 + j) * 512);
        }
        // ---- A fragments straight from global (coalesced 1024B, no barrier dep)
        short8 a0[2], a1[2];
        #pragma unroll
        for (int mf = 0; mf < 2; mf++) {
            a0[mf] = *(const short8*)(pA[mf] + (size_t)(p * 8 + kc * 2 + 0) * 512);
            a1[mf] = *(const short8*)(pA[mf] + (size_t)(p * 8 + kc * 2 + 1) * 512);
        }
        // ---- compute: 2 K=32 sub-steps from B buffer
        #pragma unroll
        for (int ks = 0; ks < 2; ks++) {
            short8 bc[2], bsn[2];
            const int ci = (ks * 4 + lhi) ^ (lrow & 7);
            #pragma unroll
            for (int nf = 0; nf < 2; nf++) {
                bc[nf]  = *(const short8*)(BsB + buf * BSZ +
                    (nf * 16 + lrow) * 64 + ci * 8);
                bsn[nf] = *(const short8*)(BsB + buf * BSZ + FT * 64 +
                    (nf * 16 + lrow) * 64 + ci * 8);
            }
            #pragma unroll
            for (int mf = 0; mf < 2; mf++) {
                const short8 a = ks ? a1[mf] : a0[mf];
                #pragma unroll
                for (int nf = 0; nf < 2; nf++) {
                    aC[p][mf][nf] = __builtin_amdgcn_mfma_f32_16x16x32_bf16(
                        a, bc[nf], aC[p][mf][nf], 0, 0, 0);
                    aS[p][mf][nf] = __builtin_amdgcn_mfma_f32_16x16x32_bf16(
                        a, bsn[nf], aS[p][mf][nf], 0, 0, 0);
                }
            }
        }
        __syncthreads();                        // B dbuf swap
        buf ^= 1;
    }

    // ---- epilogue: f (<=128) direct, 256-f mirror; float4 over 4 t
    #pragma unroll
    for (int mf = 0; mf < 2; mf++) {
        int m0 = tileM * MT + wid * 32 + mf * 16 + lhi * 4;
        int b = m0 / TFRAMES;
        int t = m0 - b * TFRAMES;               // %4==0, run stays in batch
        #pragma unroll
        for (int nf = 0; nf < 2; nf++) {
            int f = tileF * FT + nf * 16 + lrow;
            float4 od, om;
            #pragma unroll
            for (int q = 0; q < 4; q++) {
                const float Ce = aC[0][mf][nf][q], Co = aC[1][mf][nf][q];
                const float Se = aS[0][mf][nf][q], So = aS[1][mf][nf][q];
                const float rd = Ce + Co, id = Se + So;
                const float rm = Ce - Co, im = So - Se;
                (&od.x)[q] = sqrtf(rd * rd + id * id);
                (&om.x)[q] = sqrtf(rm * rm + im * im);
            }
            if (f <= 128)
                *(float4*)(mag + ((size_t)b * NFREQ + f) * TFRAMES + t) = od;
            if (f <= 127)
                *(float4*)(mag + ((size_t)b * NFREQ + (256 - f)) * TFRAMES + t) = om;
        }
    }
}

// ------------------------------------------- normalize: warp-per-row, f4 ----
__global__ __launch_bounds__(256) void normalize(const float* __restrict__ mag,
                                                 float* __restrict__ feat)
{
    const int row = blockIdx.x * 4 + (threadIdx.x >> 6);    // b*NFREQ+f
    const int lane = threadIdx.x & 63;
    const float* mp = mag + (size_t)row * TFRAMES;

    float4 v[3];
    float sum = 0.f;
    #pragma unroll
    for (int i = 0; i < 3; i++) {
        int c4 = lane + i * 64;                 // 156 float4 per row
        if (c4 < TFRAMES / 4) {
            float4 t = *(const float4*)(mp + c4 * 4);
            t.x = fmaxf(t.x, EPS); t.y = fmaxf(t.y, EPS);
            t.z = fmaxf(t.z, EPS); t.w = fmaxf(t.w, EPS);
            v[i] = t;
            sum += (t.x + t.y) + (t.z + t.w);
        } else {
            v[i] = make_float4(0.f, 0.f, 0.f, 0.f);
        }
    }
    #pragma unroll
    for (int off = 1; off < 64; off <<= 1) sum += __shfl_xor(sum, off, 64);
    const float mean = sum * (1.0f / (float)TFRAMES);

    float ssd = 0.f;
    #pragma unroll
    for (int i = 0; i < 3; i++) {
        int c4 = lane + i * 64;
        if (c4 < TFRAMES / 4) {
            float dx = v[i].x - mean, dy = v[i].y - mean;
            float dz = v[i].z - mean, dw = v[i].w - mean;
            ssd += (dx * dx + dy * dy) + (dz * dz + dw * dw);
        }
    }
    #pragma unroll
    for (int off = 1; off < 64; off <<= 1) ssd += __shfl_xor(ssd, off, 64);
    const float stdv = sqrtf(ssd * (1.0f / (float)(TFRAMES - 1)));
    const float inv = 1.0f / (stdv + EPS);

    float* fp = feat + (size_t)row * TFRAMES;
    #pragma unroll
    for (int i = 0; i < 3; i++) {
        int c4 = lane + i * 64;
        if (c4 < TFRAMES / 4) {
            float4 o;
            o.x = (v[i].x - mean) * inv; o.y = (v[i].y - mean) * inv;
            o.z = (v[i].z - mean) * inv; o.w = (v[i].w - mean) * inv;
            *(float4*)(fp + c4 * 4) = o;
        }
    }
}

// ---------------------------------------------------------------- launch ----
extern "C" void kernel_launch(void* const* d_in, const int* in_sizes, int n_in,
                              void* d_out, int out_size, void* d_ws, size_t ws_size,
                              hipStream_t stream) {
    const float* x = (const float*)d_in[0];
    unsigned short* Wec = (unsigned short*)d_ws;            // [160][256] bf16
    unsigned short* Wes = Wec + 160 * KH;
    unsigned short* Woc = Wes + 160 * KH;
    unsigned short* Wos = Woc + 160 * KH;
    unsigned short* xT  = Wos + 160 * KH;                   // 2496*2*8*512 bf16
    float* mag  = (float*)d_out;                            // [64][257][624]
    float* feat = mag + (size_t)NBATCH * NFREQ * TFRAMES;

    prep<<<XBLKS + 160, 256, 0, stream>>>(x, xT, Wec, Wes, Woc, Wos);

    // 312 M-tiles x 5 F-tiles, linearized + XCD-swizzled in-kernel
    stft_mfma<<<312 * 5, 256, 0, stream>>>(xT, Wec, Wes, Woc, Wos, mag);

    normalize<<<NBATCH * NFREQ / 4, 256, 0, stream>>>(mag, feat);
}

// Round 16
// 51.974 us; speedup vs baseline: 1.2585x; 1.1278x over previous
//
#include <hip/hip_runtime.h>
#include <math.h>

#define FRAME_LEN 512
#define HOP       256
#define NFREQ     257
#define NBATCH    64
#define NSAMP     160000
#define NSQ       40000        // samples per residue per batch
#define TFRAMES   624
#define EPS       1.1920928955078125e-07f

#define MT 128                 // frames per tile; 312 M-tiles
#define FT 32                  // freq bins per tile; 3 f-tiles (f 0..64 pad 96)
#define BK 64                  // k' chunk per stage
#define RS 2560000             // shorts per residue array (64*40000)
#define TS 12288               // shorts per table (96*128)
#define TBLKS 96
#define XBLKS 2500             // x blocks: 16 f32/thread

#define ASZ (MT * BK)          // shorts per A buffer (8192)
#define BSZ (2 * FT * BK)      // shorts per B buffer (4096)

typedef __attribute__((ext_vector_type(8))) short short8;   // 8 bf16
typedef __attribute__((ext_vector_type(4))) float f32x4;    // MFMA acc

static __device__ __forceinline__ unsigned int f2bf(float f) {
    unsigned int u = __float_as_uint(f);
    return (u + 0x7fffu + ((u >> 16) & 1u)) >> 16;          // RNE to bf16
}
static __device__ __forceinline__ void gload_lds16(const void* g, void* l) {
    __builtin_amdgcn_global_load_lds(
        (const __attribute__((address_space(1))) void*)g,
        (__attribute__((address_space(3))) void*)l, 16, 0, 0);
}

// ---- prep: tables W[r][cs][96][128] + x de-interleaved mod 4 -> xq[r] ------
__global__ __launch_bounds__(256) void prep(const float* __restrict__ x,
                                            unsigned short* __restrict__ xq,
                                            unsigned short* __restrict__ Wt) {
    if (blockIdx.x < TBLKS) {                   // tables; f<=64 live, rest 0
        const int f = blockIdx.x;               // 0..95
        #pragma unroll
        for (int h = 0; h < 2; h++) {
            const int n = threadIdx.x + h * 256;        // 0..511
            unsigned short cb = 0, sb = 0;
            if (f <= 64) {
                float w = 0.5f * (1.0f - cosf(2.0f * (float)M_PI * (float)n / (float)FRAME_LEN));
                float ang = (float)((f * n) & (FRAME_LEN - 1)) * (2.0f * (float)M_PI / (float)FRAME_LEN);
                float sv, cv;
                sincosf(ang, &sv, &cv);
                cb = (unsigned short)f2bf(cv * w);
                sb = (unsigned short)f2bf(sv * w);      // i = +sin convention
            }
            const int r = n & 3, q = n >> 2;
            Wt[(r * 2 + 0) * TS + f * 128 + q] = cb;
            Wt[(r * 2 + 1) * TS + f * 128 + q] = sb;
        }
    } else {                                    // 16 f32/thread, mod-4 split
        const int i = (blockIdx.x - TBLKS) * 256 + threadIdx.x;
        const int g = i * 16;
        const int b = g / NSAMP;
        const int s = g - b * NSAMP;            // 160000%16==0: one batch
        const float4* src = (const float4*)(x + (size_t)b * NSAMP + s);
        const float4 v0 = src[0], v1 = src[1], v2 = src[2], v3 = src[3];
        const size_t o = (size_t)b * NSQ + (s >> 2);
        uint2 p;
        p.x = f2bf(v0.x) | (f2bf(v1.x) << 16);
        p.y = f2bf(v2.x) | (f2bf(v3.x) << 16);
        *(uint2*)(xq + 0 * (size_t)RS + o) = p;
        p.x = f2bf(v0.y) | (f2bf(v1.y) << 16);
        p.y = f2bf(v2.y) | (f2bf(v3.y) << 16);
        *(uint2*)(xq + 1 * (size_t)RS + o) = p;
        p.x = f2bf(v0.z) | (f2bf(v1.z) << 16);
        p.y = f2bf(v2.z) | (f2bf(v3.z) << 16);
        *(uint2*)(xq + 2 * (size_t)RS + o) = p;
        p.x = f2bf(v0.w) | (f2bf(v1.w) << 16);
        p.y = f2bf(v2.w) | (f2bf(v3.w) << 16);
        *(uint2*)(xq + 3 * (size_t)RS + o) = p;
    }
}

// ---- stft: radix-4 symmetry — r10 inner loop, 4-bin epilogue ---------------
__global__ __launch_bounds__(256) void stft_mfma(
    const unsigned short* __restrict__ xq, const unsigned short* __restrict__ Wt,
    float* __restrict__ mag)
{
    __shared__ unsigned short As[2][MT][BK];    // 32 KB, linear gload dest
    __shared__ unsigned short Bs[2][2][FT][BK]; // 16 KB (cos, sin)

    const int tid = threadIdx.x;
    // XCD swizzle: nwg=936=8*117; 3 consecutive logicals share an A-tile.
    const int logical = ((int)blockIdx.x & 7) * 117 + ((int)blockIdx.x >> 3);
    const int tileM = logical / 3;              // 0..311
    const int tileF = logical % 3;              // 0..2
    const int wid = tid >> 6;
    const int lane = tid & 63;
    const int lrow = lane & 15;
    const int lhi = lane >> 4;

    unsigned short* AsB = &As[0][0][0];
    unsigned short* BsB = &Bs[0][0][0][0];

    // residue-0 staging sources (XOR chunk swizzle on SOURCE; dest linear);
    // residue r / k-chunk kc add the compile-time constant r*RS + kc*64.
    const unsigned short* pA[4];
    #pragma unroll
    for (int j = 0; j < 4; j++) {
        int idx = wid * 4 + j;                  // 0..15, 8 rows each
        int row = idx * 8 + (lane >> 3);
        int m = tileM * MT + row;               // < 39936 exact
        int b = m / TFRAMES;
        int t = m - b * TFRAMES;
        int chunk = (lane & 7) ^ (row & 7);
        pA[j] = xq + (size_t)b * NSQ + t * (HOP / 4) + chunk * 8;
    }
    const unsigned short* pB[2];
    #pragma unroll
    for (int j = 0; j < 2; j++) {
        int i = wid * 2 + j;                    // 0..7: 0-3 cos, 4-7 sin
        int row = (i & 3) * 8 + (lane >> 3);
        int fg = tileF * FT + row;              // < 96 (padded tables)
        int chunk = (lane & 7) ^ (row & 7);
        pB[j] = Wt + ((i & 4) ? TS : 0) + fg * 128 + chunk * 8;
    }

    f32x4 aC[4][2][2] = {};                     // [residue][mf][nf]
    f32x4 aS[4][2][2] = {};

    // ---- prologue: stage (residue 0, kc 0) into buf 0
    #pragma unroll
    for (int j = 0; j < 4; j++)
        gload_lds16(pA[j], AsB + (wid * 4 + j) * 512);
    #pragma unroll
    for (int j = 0; j < 2; j++)
        gload_lds16(pB[j], BsB + (wid * 2 + j) * 512);
    __syncthreads();

    int buf = 0;
    #pragma unroll
    for (int it = 0; it < 8; it++) {
        const int R = it >> 1;                  // residue (compile-time)
        // ---- stage next (residue, chunk) into other buffer
        if (it < 7) {
            const int Rn = (it + 1) >> 1;
            const int kn = ((it + 1) & 1) * BK;
            const size_t aoff = (size_t)Rn * RS + kn;
            const size_t boff = (size_t)Rn * (2 * TS) + kn;
            #pragma unroll
            for (int j = 0; j < 4; j++)
                gload_lds16(pA[j] + aoff, AsB + (buf ^ 1) * ASZ + (wid * 4 + j) * 512);
            #pragma unroll
            for (int j = 0; j < 2; j++)
                gload_lds16(pB[j] + boff, BsB + (buf ^ 1) * BSZ + (wid * 2 + j) * 512);
        }
        // ---- compute current buffer into residue-R accumulators
        #pragma unroll
        for (int ks = 0; ks < 2; ks++) {
            short8 a[2], bc[2], bsn[2];
            const int c = (ks * 4 + lhi) ^ (lrow & 7);
            #pragma unroll
            for (int mf = 0; mf < 2; mf++)
                a[mf] = *(const short8*)(AsB + buf * ASZ +
                    (wid * 32 + mf * 16 + lrow) * BK + c * 8);
            #pragma unroll
            for (int nf = 0; nf < 2; nf++) {
                bc[nf]  = *(const short8*)(BsB + buf * BSZ +
                    (nf * 16 + lrow) * BK + c * 8);
                bsn[nf] = *(const short8*)(BsB + buf * BSZ + FT * BK +
                    (nf * 16 + lrow) * BK + c * 8);
            }
            #pragma unroll
            for (int mf = 0; mf < 2; mf++) {
                #pragma unroll
                for (int nf = 0; nf < 2; nf++) {
                    aC[R][mf][nf] = __builtin_amdgcn_mfma_f32_16x16x32_bf16(
                        a[mf], bc[nf], aC[R][mf][nf], 0, 0, 0);
                    aS[R][mf][nf] = __builtin_amdgcn_mfma_f32_16x16x32_bf16(
                        a[mf], bsn[nf], aS[R][mf][nf], 0, 0, 0);
                }
            }
        }
        __syncthreads();                        // next buffer landed; reads done
        buf ^= 1;
    }

    // ---- epilogue: 4 bins per f<=64 via quarter-period sign combos
    #pragma unroll
    for (int mf = 0; mf < 2; mf++) {
        int m0 = tileM * MT + wid * 32 + mf * 16 + lhi * 4;
        int b = m0 / TFRAMES;
        int t = m0 - b * TFRAMES;               // %4==0, run stays in batch
        float* magb = mag + (size_t)b * NFREQ * TFRAMES + t;
        #pragma unroll
        for (int nf = 0; nf < 2; nf++) {
            int f = tileF * FT + nf * 16 + lrow;    // 0..95
            float4 o1, o2, o3, o4;
            #pragma unroll
            for (int q = 0; q < 4; q++) {
                const float C0 = aC[0][mf][nf][q], C1 = aC[1][mf][nf][q];
                const float C2 = aC[2][mf][nf][q], C3 = aC[3][mf][nf][q];
                const float S0 = aS[0][mf][nf][q], S1 = aS[1][mf][nf][q];
                const float S2 = aS[2][mf][nf][q], S3 = aS[3][mf][nf][q];
                float r, i2;
                r = (C0 + C2) + (C1 + C3); i2 = (S0 + S2) + (S1 + S3);  // f
                (&o1.x)[q] = sqrtf(r * r + i2 * i2);
                r = (C0 - C2) + (S1 - S3); i2 = (C1 - C3) - (S0 - S2);  // 128-f
                (&o2.x)[q] = sqrtf(r * r + i2 * i2);
                r = (C0 - C2) - (S1 - S3); i2 = (C1 - C3) + (S0 - S2);  // 128+f
                (&o3.x)[q] = sqrtf(r * r + i2 * i2);
                r = (C0 + C2) - (C1 + C3); i2 = (S1 + S3) - (S0 + S2);  // 256-f
                (&o4.x)[q] = sqrtf(r * r + i2 * i2);
            }
            if (f <= 64)           *(float4*)(magb + (size_t)f * TFRAMES) = o1;
            if (f <= 63)           *(float4*)(magb + (size_t)(128 - f) * TFRAMES) = o2;
            if (f >= 1 && f <= 64) *(float4*)(magb + (size_t)(128 + f) * TFRAMES) = o3;
            if (f <= 63)           *(float4*)(magb + (size_t)(256 - f) * TFRAMES) = o4;
        }
    }
}

// ------------------------------------------- normalize: warp-per-row, f4 ----
__global__ __launch_bounds__(256) void normalize(const float* __restrict__ mag,
                                                 float* __restrict__ feat)
{
    const int row = blockIdx.x * 4 + (threadIdx.x >> 6);    // b*NFREQ+f
    const int lane = threadIdx.x & 63;
    const float* mp = mag + (size_t)row * TFRAMES;

    float4 v[3];
    float sum = 0.f;
    #pragma unroll
    for (int i = 0; i < 3; i++) {
        int c4 = lane + i * 64;                 // 156 float4 per row
        if (c4 < TFRAMES / 4) {
            float4 t = *(const float4*)(mp + c4 * 4);
            t.x = fmaxf(t.x, EPS); t.y = fmaxf(t.y, EPS);
            t.z = fmaxf(t.z, EPS); t.w = fmaxf(t.w, EPS);
            v[i] = t;
            sum += (t.x + t.y) + (t.z + t.w);
        } else {
            v[i] = make_float4(0.f, 0.f, 0.f, 0.f);
        }
    }
    #pragma unroll
    for (int off = 1; off < 64; off <<= 1) sum += __shfl_xor(sum, off, 64);
    const float mean = sum * (1.0f / (float)TFRAMES);

    float ssd = 0.f;
    #pragma unroll
    for (int i = 0; i < 3; i++) {
        int c4 = lane + i * 64;
        if (c4 < TFRAMES / 4) {
            float dx = v[i].x - mean, dy = v[i].y - mean;
            float dz = v[i].z - mean, dw = v[i].w - mean;
            ssd += (dx * dx + dy * dy) + (dz * dz + dw * dw);
        }
    }
    #pragma unroll
    for (int off = 1; off < 64; off <<= 1) ssd += __shfl_xor(ssd, off, 64);
    const float stdv = sqrtf(ssd * (1.0f / (float)(TFRAMES - 1)));
    const float inv = 1.0f / (stdv + EPS);

    float* fp = feat + (size_t)row * TFRAMES;
    #pragma unroll
    for (int i = 0; i < 3; i++) {
        int c4 = lane + i * 64;
        if (c4 < TFRAMES / 4) {
            float4 o;
            o.x = (v[i].x - mean) * inv; o.y = (v[i].y - mean) * inv;
            o.z = (v[i].z - mean) * inv; o.w = (v[i].w - mean) * inv;
            *(float4*)(fp + c4 * 4) = o;
        }
    }
}

// ---------------------------------------------------------------- launch ----
extern "C" void kernel_launch(void* const* d_in, const int* in_sizes, int n_in,
                              void* d_out, int out_size, void* d_ws, size_t ws_size,
                              hipStream_t stream) {
    const float* x = (const float*)d_in[0];
    unsigned short* Wt = (unsigned short*)d_ws;             // 8 tables [96][128]
    unsigned short* xq = Wt + 8 * TS;                       // 4 x [64][40000]
    float* mag  = (float*)d_out;                            // [64][257][624]
    float* feat = mag + (size_t)NBATCH * NFREQ * TFRAMES;

    prep<<<TBLKS + XBLKS, 256, 0, stream>>>(x, xq, Wt);

    // 312 M-tiles x 3 F-tiles, linearized + XCD-swizzled in-kernel
    stft_mfma<<<312 * 3, 256, 0, stream>>>(xq, Wt, mag);

    normalize<<<NBATCH * NFREQ / 4, 256, 0, stream>>>(mag, feat);
}